// Round 10
// baseline (183.745 us; speedup 1.0000x reference)
//
#include <hip/hip_runtime.h>
#include <hip/hip_fp8.h>

#define NB   4
#define NT   8
#define NPTS 16384
#define NK   16
#define GRAD_COUNT 8388608.0f   // T*N*K*C per batch

// ---- workspace layout (bytes) ----
// P     : [B][N] 64-B fp8 field blocks (4 x uint4)       = 4 MB
// REC4  : [B][N][K] u32 {j | bf16(inv_d)<<16}            = 4 MB
// partA : [B][1024][2] f32 (grad partials)               = 32 KB
// partB : [B][256][2]  f32 (rl2 partials)                = 8 KB
// CNT   : u32 finalize counter                           = 64 B
#define P_BYTES     (NB * NPTS * 64)
#define REC_OFF_B   P_BYTES
#define PARTA_OFF_B (REC_OFF_B + NB * NPTS * NK * 4)
#define PARTB_OFF_B (PARTA_OFF_B + 32768)
#define CNT_OFF_B   (PARTB_OFF_B + 8192)
#define WS_NEEDED   (CNT_OFF_B + 64)

#define PACK_BLOCKS 1024
#define DIST_BLOCKS 4096
#define PREP_BLOCKS (PACK_BLOCKS + DIST_BLOCKS)
#define GRAD_BLOCKS 4096

#if defined(__has_builtin)
#if __has_builtin(__builtin_amdgcn_cvt_pk_f32_fp8) && __has_builtin(__builtin_amdgcn_cvt_pk_fp8_f32)
#define USE_FP8_BUILTINS 1
#endif
#endif

typedef float vf2 __attribute__((ext_vector_type(2)));

__device__ __forceinline__ unsigned pack4_fp8(float a, float b, float c, float d) {
#ifdef USE_FP8_BUILTINS
    int u = __builtin_amdgcn_cvt_pk_fp8_f32(a, b, 0, false);
    u     = __builtin_amdgcn_cvt_pk_fp8_f32(c, d, u, true);
    return (unsigned)u;
#else
    __hip_fp8_e4m3 ha(a), hb(b), hc(c), hd(d);
    return (unsigned)ha.__x | ((unsigned)hb.__x << 8) |
           ((unsigned)hc.__x << 16) | ((unsigned)hd.__x << 24);
#endif
}

__device__ __forceinline__ float absdiff4(unsigned a, unsigned b) {
#ifdef USE_FP8_BUILTINS
    vf2 a0 = __builtin_amdgcn_cvt_pk_f32_fp8((int)a, false);
    vf2 a1 = __builtin_amdgcn_cvt_pk_f32_fp8((int)a, true);
    vf2 b0 = __builtin_amdgcn_cvt_pk_f32_fp8((int)b, false);
    vf2 b1 = __builtin_amdgcn_cvt_pk_f32_fp8((int)b, true);
    return fabsf(a0.x - b0.x) + fabsf(a0.y - b0.y) +
           fabsf(a1.x - b1.x) + fabsf(a1.y - b1.y);
#else
    float s = 0.f;
    #pragma unroll
    for (int i = 0; i < 4; ++i) {
        __hip_fp8_e4m3 ha, hb;
        ha.__x = (a >> (8 * i)) & 0xff;
        hb.__x = (b >> (8 * i)) & 0xff;
        s += fabsf((float)ha - (float)hb);
    }
    return s;
#endif
}

// =================== prep: pack blocks || dist blocks ===================

__global__ __launch_bounds__(256) void sobolev_prep(
    const float4* __restrict__ pred,
    const float4* __restrict__ target,
    const float*  __restrict__ pos,
    const int*    __restrict__ knn,
    uint4*    __restrict__ P,        // [b][n] 4 x uint4
    unsigned* __restrict__ REC4,     // [b][n][k]
    float*    __restrict__ partB,    // [b][256][2]
    unsigned* __restrict__ cnt)
{
    if (blockIdx.x == 0 && threadIdx.x == 0) *cnt = 0;   // re-zero each call

    if (blockIdx.x < PACK_BLOCKS) {
        // ---- pack fields to fp8 + rl2 partials ----
        const int blk = blockIdx.x;            // b-major
        const int b   = blk >> 8;
        const int n   = ((blk & 255) << 6) + (threadIdx.x >> 2);
        const int q   = threadIdx.x & 3;       // lane q owns t = q, q+4

        const float4 pv0 = pred  [(b * NT + q    ) * NPTS + n];
        const float4 pv1 = pred  [(b * NT + q + 4) * NPTS + n];
        const float4 tv0 = target[(b * NT + q    ) * NPTS + n];
        const float4 tv1 = target[(b * NT + q + 4) * NPTS + n];

        uint4 ck;
        ck.x = pack4_fp8(pv0.x, pv0.y, pv0.z, pv0.w);
        ck.y = pack4_fp8(pv1.x, pv1.y, pv1.z, pv1.w);
        ck.z = pack4_fp8(tv0.x, tv0.y, tv0.z, tv0.w);
        ck.w = pack4_fp8(tv1.x, tv1.y, tv1.z, tv1.w);
        P[((size_t)(b * NPTS + n) << 2) + q] = ck;

        float sd, st;
        {
            const float e0 = pv0.x - tv0.x, e1 = pv0.y - tv0.y,
                        e2 = pv0.z - tv0.z, e3 = pv0.w - tv0.w;
            const float f0 = pv1.x - tv1.x, f1 = pv1.y - tv1.y,
                        f2 = pv1.z - tv1.z, f3 = pv1.w - tv1.w;
            sd = e0*e0 + e1*e1 + e2*e2 + e3*e3 + f0*f0 + f1*f1 + f2*f2 + f3*f3;
            st = tv0.x*tv0.x + tv0.y*tv0.y + tv0.z*tv0.z + tv0.w*tv0.w +
                 tv1.x*tv1.x + tv1.y*tv1.y + tv1.z*tv1.z + tv1.w*tv1.w;
        }

        __shared__ float lds[4][2];
        const int wave = threadIdx.x >> 6, lane = threadIdx.x & 63;
        #pragma unroll
        for (int o = 32; o > 0; o >>= 1) {
            sd += __shfl_down(sd, o);
            st += __shfl_down(st, o);
        }
        if (lane == 0) { lds[wave][0] = sd; lds[wave][1] = st; }
        __syncthreads();
        if (threadIdx.x < 2)
            partB[blk * 2 + threadIdx.x] =
                lds[0][threadIdx.x] + lds[1][threadIdx.x] +
                lds[2][threadIdx.x] + lds[3][threadIdx.x];
    } else {
        // ---- dist: per-tuple {j, bf16 inv_d} records ----
        const int t  = (blockIdx.x - PACK_BLOCKS) * 256 + threadIdx.x; // [0, B*N*K)
        const int b  = t >> 18;
        const int n  = (t >> 4) & (NPTS - 1);
        const int j  = knn[t];

        const float* pb_ = pos + (size_t)b * NPTS * 3;
        const float jx = pb_[j * 3], jy = pb_[j * 3 + 1], jz = pb_[j * 3 + 2];
        const float nx = pb_[n * 3], ny = pb_[n * 3 + 1], nz = pb_[n * 3 + 2];
        const float dx = jx - nx, dy = jy - ny, dz = jz - nz;
        const float d2 = fmaxf(dx*dx + dy*dy + dz*dz, 1e-8f);
        // d2 >= 1e-8 => sqrt >= 1e-4 > eps, so 1/max(sqrt,eps) == rsqrt
        const float inv_d = rsqrtf(d2);

        // bf16 round-to-nearest of inv_d in high 16 bits, j in low 16
        unsigned u = __float_as_uint(inv_d);
        u += 0x8000u;                       // RN (ties away; fine here)
        REC4[t] = (u & 0xffff0000u) | (unsigned)j;
    }
}

// =================== gradfin: grad (4 n / wave) + last-block finalize ===================

__global__ __launch_bounds__(256) void sobolev_gradfin(
    const uint4*    __restrict__ P,
    const unsigned* __restrict__ REC4,
    float*          __restrict__ partA,   // [b][1024][2]
    const float*    __restrict__ partB,   // [b][256][2]
    unsigned*       __restrict__ cnt,
    float*          __restrict__ out)
{
    // XCD pinning: per-XCD reused set = P(b) 1MB (+ REC4 streamed)
    const int xcd  = blockIdx.x & 7;
    const int b    = xcd >> 1;
    const int nblk = ((xcd & 1) << 9) | (blockIdx.x >> 3);   // 0..1023
    const int wave = threadIdx.x >> 6;
    const int lane = threadIdx.x & 63;
    const int k    = lane >> 2;       // 16 neighbor slots per wave
    const int q    = lane & 3;        // 4 lanes cover one 64-B block
    const int nb   = (nblk << 4) | (wave << 2);   // 4 n's per wave

    const size_t pb = (size_t)(b * NPTS);
    float v0 = 0.f, v1 = 0.f;

    #pragma unroll
    for (int i = 0; i < 4; ++i) {
        const int n = nb + i;
        const unsigned r = REC4[(((b << 14) | n) << 4) | k];
        const int j = (int)(r & 0xffffu);
        const float inv_d = __uint_as_float(r & 0xffff0000u);

        const uint4 gj = P[((pb + j) << 2) + q];
        const uint4 gn = P[((pb + n) << 2) + q];

        const float sp = absdiff4(gj.x, gn.x) + absdiff4(gj.y, gn.y);
        const float st = absdiff4(gj.z, gn.z) + absdiff4(gj.w, gn.w);
        v0 += sp * inv_d;
        v1 += st * inv_d;
    }

    __shared__ float lds[4][2];
    #pragma unroll
    for (int o = 32; o > 0; o >>= 1) {
        v0 += __shfl_down(v0, o);
        v1 += __shfl_down(v1, o);
    }
    if (lane == 0) { lds[wave][0] = v0; lds[wave][1] = v1; }
    __syncthreads();
    if (threadIdx.x < 2) {
        const int slot = (b << 10) | nblk;
        partA[slot * 2 + threadIdx.x] =
            lds[0][threadIdx.x] + lds[1][threadIdx.x] +
            lds[2][threadIdx.x] + lds[3][threadIdx.x];
    }

    // ---- last-block finalize ----
    __shared__ bool amLast;
    if (threadIdx.x == 0) {
        __threadfence();
        const unsigned prev = __hip_atomic_fetch_add(
            cnt, 1u, __ATOMIC_ACQ_REL, __HIP_MEMORY_SCOPE_AGENT);
        amLast = (prev == (unsigned)(GRAD_BLOCKS - 1));
    }
    __syncthreads();
    if (!amLast) return;
    __threadfence();

    const int tid = threadIdx.x;
    __shared__ float acc[NB][4];   // [b][{pg,tg,sd,st}]
    __shared__ float red[4][4];

    for (int bb = 0; bb < NB; ++bb) {
        float pg = 0.f, tg = 0.f;
        const float2* pa2 = (const float2*)(partA + bb * 1024 * 2);
        #pragma unroll
        for (int i = 0; i < 4; ++i) {
            const float2 v = pa2[i * 256 + tid];
            pg += v.x; tg += v.y;
        }
        const float2 vb = ((const float2*)(partB + bb * 256 * 2))[tid];
        float sd = vb.x, st = vb.y;

        #pragma unroll
        for (int o = 32; o > 0; o >>= 1) {
            pg += __shfl_down(pg, o); tg += __shfl_down(tg, o);
            sd += __shfl_down(sd, o); st += __shfl_down(st, o);
        }
        const int wv = tid >> 6, ln = tid & 63;
        if (ln == 0) {
            red[wv][0] = pg; red[wv][1] = tg;
            red[wv][2] = sd; red[wv][3] = st;
        }
        __syncthreads();
        if (tid < 4)
            acc[bb][tid] = red[0][tid] + red[1][tid] + red[2][tid] + red[3][tid];
        __syncthreads();
    }

    if (tid == 0) {
        float rl2 = 0.f, ge = 0.f;
        const float inv_cnt = 1.0f / GRAD_COUNT;
        #pragma unroll
        for (int bb = 0; bb < NB; ++bb) {
            const float pg = acc[bb][0] * inv_cnt;
            const float tg = acc[bb][1] * inv_cnt;
            rl2 += sqrtf(acc[bb][2]) / fmaxf(sqrtf(acc[bb][3]), 1e-8f);
            ge  += fabsf(pg - tg) / fmaxf(tg, 1e-8f);
        }
        out[0] = rl2 * 0.25f + 0.1f * (ge * 0.25f);
    }
}

// =================== fallback path (if ws too small) ===================

__global__ __launch_bounds__(256) void sobolev_main_fb(
    const float4* __restrict__ pred,
    const float4* __restrict__ target,
    const int*    __restrict__ knn,
    const float*  __restrict__ pos,
    float*        __restrict__ part)
{
    const int xcd   = blockIdx.x & 7;
    const int s     = blockIdx.x >> 3;
    const int b     = xcd >> 1;
    const int thalf = xcd & 1;
    const int w     = s * 256 + threadIdx.x;
    const int k     = w & (NK - 1);
    const int n     = w >> 4;
    const int j     = knn[(b << 18) + w];

    const float* pc = pos + (b * NPTS + n) * 3;
    const float* pj = pos + (b * NPTS + j) * 3;
    const float dx = pj[0] - pc[0], dy = pj[1] - pc[1], dz = pj[2] - pc[2];
    const float d2   = fmaxf(dx*dx + dy*dy + dz*dz, 1e-8f);
    const float dist = fmaxf(sqrtf(d2), 1e-8f);
    const float inv_d = 1.0f / dist;

    float pg_abs = 0.f, tg_abs = 0.f, sd = 0.f, st = 0.f;
    const bool do_l2 = (k == 0);
    const int t0 = thalf * 4;
    #pragma unroll
    for (int tt = 0; tt < 4; ++tt) {
        const int base = (b * NT + t0 + tt) * NPTS;
        const float4 pcv = pred[base + n];
        const float4 pjv = pred[base + j];
        const float4 tcv = target[base + n];
        const float4 tjv = target[base + j];
        pg_abs += fabsf(pjv.x-pcv.x)+fabsf(pjv.y-pcv.y)+fabsf(pjv.z-pcv.z)+fabsf(pjv.w-pcv.w);
        tg_abs += fabsf(tjv.x-tcv.x)+fabsf(tjv.y-tcv.y)+fabsf(tjv.z-tcv.z)+fabsf(tjv.w-tcv.w);
        if (do_l2) {
            const float ex = pcv.x-tcv.x, ey = pcv.y-tcv.y, ez = pcv.z-tcv.z, ew = pcv.w-tcv.w;
            sd += ex*ex + ey*ey + ez*ez + ew*ew;
            st += tcv.x*tcv.x + tcv.y*tcv.y + tcv.z*tcv.z + tcv.w*tcv.w;
        }
    }
    float vals[4] = { pg_abs * inv_d, tg_abs * inv_d, sd, st };
    __shared__ float lds[4][4];
    const int wave = threadIdx.x >> 6, lane = threadIdx.x & 63;
    #pragma unroll
    for (int c = 0; c < 4; ++c) {
        float v = vals[c];
        #pragma unroll
        for (int o = 32; o > 0; o >>= 1) v += __shfl_down(v, o);
        if (lane == 0) lds[wave][c] = v;
    }
    __syncthreads();
    if (threadIdx.x < 4) {
        const int slot = (xcd << 10) | s;
        part[slot * 4 + threadIdx.x] =
            lds[0][threadIdx.x] + lds[1][threadIdx.x] +
            lds[2][threadIdx.x] + lds[3][threadIdx.x];
    }
}

__global__ __launch_bounds__(256) void sobolev_finalize_fb(
    const float* __restrict__ part, float* __restrict__ out)
{
    __shared__ float sums_s[16];
    __shared__ float lred[4];
    const int tid = threadIdx.x;
    for (int bc = 0; bc < 16; ++bc) {
        const int b = bc >> 2, comp = bc & 3;
        float s = 0.f;
        for (int i = tid; i < 2048; i += 256)
            s += part[(b * 2048 + i) * 4 + comp];
        #pragma unroll
        for (int o = 32; o > 0; o >>= 1) s += __shfl_down(s, o);
        const int wave = tid >> 6, lane = tid & 63;
        if (lane == 0) lred[wave] = s;
        __syncthreads();
        if (tid == 0) sums_s[bc] = lred[0] + lred[1] + lred[2] + lred[3];
        __syncthreads();
    }
    if (tid == 0) {
        float rl2 = 0.f, ge = 0.f;
        const float inv_cnt = 1.0f / GRAD_COUNT;
        #pragma unroll
        for (int b = 0; b < NB; ++b) {
            const float pg = sums_s[b*4+0] * inv_cnt;
            const float tg = sums_s[b*4+1] * inv_cnt;
            rl2 += sqrtf(sums_s[b*4+2]) / fmaxf(sqrtf(sums_s[b*4+3]), 1e-8f);
            ge  += fabsf(pg - tg) / fmaxf(tg, 1e-8f);
        }
        out[0] = rl2 * 0.25f + 0.1f * (ge * 0.25f);
    }
}

// =================== launch ===================

extern "C" void kernel_launch(void* const* d_in, const int* in_sizes, int n_in,
                              void* d_out, int out_size, void* d_ws, size_t ws_size,
                              hipStream_t stream) {
    const float4* pred   = (const float4*)d_in[0];
    const float4* target = (const float4*)d_in[1];
    const int*    knn    = (const int*)d_in[2];
    const float*  pos    = (const float*)d_in[3];
    float* out = (float*)d_out;

    if (ws_size >= (size_t)WS_NEEDED) {
        uint4*    P     = (uint4*)d_ws;
        unsigned* REC4  = (unsigned*)((char*)d_ws + REC_OFF_B);
        float*    partA = (float*)((char*)d_ws + PARTA_OFF_B);
        float*    partB = (float*)((char*)d_ws + PARTB_OFF_B);
        unsigned* cnt   = (unsigned*)((char*)d_ws + CNT_OFF_B);

        sobolev_prep<<<PREP_BLOCKS, 256, 0, stream>>>(pred, target, pos, knn,
                                                      P, REC4, partB, cnt);
        sobolev_gradfin<<<GRAD_BLOCKS, 256, 0, stream>>>(P, REC4, partA, partB,
                                                         cnt, out);
    } else {
        float* part = (float*)d_ws;      // 8192*4 floats = 128 KB
        sobolev_main_fb<<<8192, 256, 0, stream>>>(pred, target, knn, pos, part);
        sobolev_finalize_fb<<<1, 256, 0, stream>>>(part, out);
    }
}

// Round 11
// 34.847 us; speedup vs baseline: 5.2729x; 5.2729x over previous
//
#include <hip/hip_runtime.h>
#include <hip/hip_fp8.h>

#define NB   4
#define NT   8
#define NPTS 16384
#define NK   16
#define GRAD_COUNT 8388608.0f   // T*N*K*C per batch

// ---- workspace layout (bytes) ----
// P     : [B][N] 64-B fp8 field blocks (4 x uint4)       = 4 MB
// REC4  : [B][N][K] u32 {bf16(inv_d)<<16 | j}            = 4 MB
// partA : [B][1024][2] f32 (grad partials)               = 32 KB
// partB : [B][256][2]  f32 (rl2 partials)                = 8 KB
#define P_BYTES     (NB * NPTS * 64)
#define REC_OFF_B   P_BYTES
#define PARTA_OFF_B (REC_OFF_B + NB * NPTS * NK * 4)
#define PARTB_OFF_B (PARTA_OFF_B + 32768)
#define WS_NEEDED   (PARTB_OFF_B + 8192)

#define PACK_BLOCKS 1024
#define DIST_BLOCKS 4096
#define PREP_BLOCKS (PACK_BLOCKS + DIST_BLOCKS)
#define GRAD_BLOCKS 4096

#if defined(__has_builtin)
#if __has_builtin(__builtin_amdgcn_cvt_pk_f32_fp8) && __has_builtin(__builtin_amdgcn_cvt_pk_fp8_f32)
#define USE_FP8_BUILTINS 1
#endif
#endif

typedef float vf2 __attribute__((ext_vector_type(2)));

__device__ __forceinline__ unsigned pack4_fp8(float a, float b, float c, float d) {
#ifdef USE_FP8_BUILTINS
    int u = __builtin_amdgcn_cvt_pk_fp8_f32(a, b, 0, false);
    u     = __builtin_amdgcn_cvt_pk_fp8_f32(c, d, u, true);
    return (unsigned)u;
#else
    __hip_fp8_e4m3 ha(a), hb(b), hc(c), hd(d);
    return (unsigned)ha.__x | ((unsigned)hb.__x << 8) |
           ((unsigned)hc.__x << 16) | ((unsigned)hd.__x << 24);
#endif
}

__device__ __forceinline__ float absdiff4(unsigned a, unsigned b) {
#ifdef USE_FP8_BUILTINS
    vf2 a0 = __builtin_amdgcn_cvt_pk_f32_fp8((int)a, false);
    vf2 a1 = __builtin_amdgcn_cvt_pk_f32_fp8((int)a, true);
    vf2 b0 = __builtin_amdgcn_cvt_pk_f32_fp8((int)b, false);
    vf2 b1 = __builtin_amdgcn_cvt_pk_f32_fp8((int)b, true);
    return fabsf(a0.x - b0.x) + fabsf(a0.y - b0.y) +
           fabsf(a1.x - b1.x) + fabsf(a1.y - b1.y);
#else
    float s = 0.f;
    #pragma unroll
    for (int i = 0; i < 4; ++i) {
        __hip_fp8_e4m3 ha, hb;
        ha.__x = (a >> (8 * i)) & 0xff;
        hb.__x = (b >> (8 * i)) & 0xff;
        s += fabsf((float)ha - (float)hb);
    }
    return s;
#endif
}

// =================== prep: pack blocks || dist blocks ===================

__global__ __launch_bounds__(256) void sobolev_prep(
    const float4* __restrict__ pred,
    const float4* __restrict__ target,
    const float*  __restrict__ pos,
    const int*    __restrict__ knn,
    uint4*    __restrict__ P,        // [b][n] 4 x uint4
    unsigned* __restrict__ REC4,     // [b][n][k]
    float*    __restrict__ partB)    // [b][256][2]
{
    if (blockIdx.x < PACK_BLOCKS) {
        // ---- pack fields to fp8 + rl2 partials ----
        const int blk = blockIdx.x;            // b-major
        const int b   = blk >> 8;
        const int n   = ((blk & 255) << 6) + (threadIdx.x >> 2);
        const int q   = threadIdx.x & 3;       // lane q owns t = q, q+4

        const float4 pv0 = pred  [(b * NT + q    ) * NPTS + n];
        const float4 pv1 = pred  [(b * NT + q + 4) * NPTS + n];
        const float4 tv0 = target[(b * NT + q    ) * NPTS + n];
        const float4 tv1 = target[(b * NT + q + 4) * NPTS + n];

        uint4 ck;
        ck.x = pack4_fp8(pv0.x, pv0.y, pv0.z, pv0.w);
        ck.y = pack4_fp8(pv1.x, pv1.y, pv1.z, pv1.w);
        ck.z = pack4_fp8(tv0.x, tv0.y, tv0.z, tv0.w);
        ck.w = pack4_fp8(tv1.x, tv1.y, tv1.z, tv1.w);
        P[((size_t)(b * NPTS + n) << 2) + q] = ck;

        float sd, st;
        {
            const float e0 = pv0.x - tv0.x, e1 = pv0.y - tv0.y,
                        e2 = pv0.z - tv0.z, e3 = pv0.w - tv0.w;
            const float f0 = pv1.x - tv1.x, f1 = pv1.y - tv1.y,
                        f2 = pv1.z - tv1.z, f3 = pv1.w - tv1.w;
            sd = e0*e0 + e1*e1 + e2*e2 + e3*e3 + f0*f0 + f1*f1 + f2*f2 + f3*f3;
            st = tv0.x*tv0.x + tv0.y*tv0.y + tv0.z*tv0.z + tv0.w*tv0.w +
                 tv1.x*tv1.x + tv1.y*tv1.y + tv1.z*tv1.z + tv1.w*tv1.w;
        }

        __shared__ float lds[4][2];
        const int wave = threadIdx.x >> 6, lane = threadIdx.x & 63;
        #pragma unroll
        for (int o = 32; o > 0; o >>= 1) {
            sd += __shfl_down(sd, o);
            st += __shfl_down(st, o);
        }
        if (lane == 0) { lds[wave][0] = sd; lds[wave][1] = st; }
        __syncthreads();
        if (threadIdx.x < 2)
            partB[blk * 2 + threadIdx.x] =
                lds[0][threadIdx.x] + lds[1][threadIdx.x] +
                lds[2][threadIdx.x] + lds[3][threadIdx.x];
    } else {
        // ---- dist: per-tuple {bf16 inv_d, j} records ----
        const int t  = (blockIdx.x - PACK_BLOCKS) * 256 + threadIdx.x; // [0, B*N*K)
        const int b  = t >> 18;
        const int n  = (t >> 4) & (NPTS - 1);
        const int j  = knn[t];

        const float* pb_ = pos + (size_t)b * NPTS * 3;
        const float jx = pb_[j * 3], jy = pb_[j * 3 + 1], jz = pb_[j * 3 + 2];
        const float nx = pb_[n * 3], ny = pb_[n * 3 + 1], nz = pb_[n * 3 + 2];
        const float dx = jx - nx, dy = jy - ny, dz = jz - nz;
        const float d2 = fmaxf(dx*dx + dy*dy + dz*dz, 1e-8f);
        // d2 >= 1e-8 => sqrt >= 1e-4 > eps, so 1/max(sqrt,eps) == rsqrt
        const float inv_d = rsqrtf(d2);

        unsigned u = __float_as_uint(inv_d);
        u += 0x8000u;                       // bf16 RN (ties away; fine here)
        REC4[t] = (u & 0xffff0000u) | (unsigned)j;
    }
}

// =================== grad: 4 n's / wave, 1 random 64-B line per tuple ===================

__global__ __launch_bounds__(256) void sobolev_grad(
    const uint4*    __restrict__ P,
    const unsigned* __restrict__ REC4,
    float*          __restrict__ partA)   // [b][1024][2]
{
    // XCD pinning: per-XCD reused set = P(b) 1MB (+ REC4 streamed)
    const int xcd  = blockIdx.x & 7;
    const int b    = xcd >> 1;
    const int nblk = ((xcd & 1) << 9) | (blockIdx.x >> 3);   // 0..1023
    const int wave = threadIdx.x >> 6;
    const int lane = threadIdx.x & 63;
    const int k    = lane >> 2;       // 16 neighbor slots per wave
    const int q    = lane & 3;        // 4 lanes cover one 64-B block
    const int nb   = (nblk << 4) | (wave << 2);   // 4 n's per wave

    const size_t pb = (size_t)(b * NPTS);
    float v0 = 0.f, v1 = 0.f;

    #pragma unroll
    for (int i = 0; i < 4; ++i) {
        const int n = nb + i;
        const unsigned r = REC4[(((b << 14) | n) << 4) | k];
        const int j = (int)(r & 0xffffu);
        const float inv_d = __uint_as_float(r & 0xffff0000u);

        const uint4 gj = P[((pb + j) << 2) + q];
        const uint4 gn = P[((pb + n) << 2) + q];

        const float sp = absdiff4(gj.x, gn.x) + absdiff4(gj.y, gn.y);
        const float st = absdiff4(gj.z, gn.z) + absdiff4(gj.w, gn.w);
        v0 += sp * inv_d;
        v1 += st * inv_d;
    }

    __shared__ float lds[4][2];
    #pragma unroll
    for (int o = 32; o > 0; o >>= 1) {
        v0 += __shfl_down(v0, o);
        v1 += __shfl_down(v1, o);
    }
    if (lane == 0) { lds[wave][0] = v0; lds[wave][1] = v1; }
    __syncthreads();
    if (threadIdx.x < 2) {
        const int slot = (b << 10) | nblk;
        partA[slot * 2 + threadIdx.x] =
            lds[0][threadIdx.x] + lds[1][threadIdx.x] +
            lds[2][threadIdx.x] + lds[3][threadIdx.x];
    }
}

// =================== final ===================

__global__ __launch_bounds__(1024) void sobolev_final(
    const float* __restrict__ partA,   // [4][1024][2]
    const float* __restrict__ partB,   // [4][256][2]
    float*       __restrict__ out)
{
    const int tid = threadIdx.x;
    __shared__ float acc[NB][4];   // [b][{pg,tg,sd,st}]
    __shared__ float red[16][4];

    for (int b = 0; b < NB; ++b) {
        float pg = 0.f, tg = 0.f, sd = 0.f, st = 0.f;
        {
            const float2 v0 = ((const float2*)(partA + b * 1024 * 2))[tid];
            pg += v0.x; tg += v0.y;
        }
        if (tid < 256) {
            const float2 vb = ((const float2*)(partB + b * 256 * 2))[tid];
            sd = vb.x; st = vb.y;
        }
        #pragma unroll
        for (int o = 32; o > 0; o >>= 1) {
            pg += __shfl_down(pg, o); tg += __shfl_down(tg, o);
            sd += __shfl_down(sd, o); st += __shfl_down(st, o);
        }
        const int wave = tid >> 6, lane = tid & 63;
        if (lane == 0) {
            red[wave][0] = pg; red[wave][1] = tg;
            red[wave][2] = sd; red[wave][3] = st;
        }
        __syncthreads();
        if (tid < 4) {
            float s = 0.f;
            #pragma unroll
            for (int w = 0; w < 16; ++w) s += red[w][tid];
            acc[b][tid] = s;
        }
        __syncthreads();
    }

    if (tid == 0) {
        float rl2 = 0.f, ge = 0.f;
        const float inv_cnt = 1.0f / GRAD_COUNT;
        #pragma unroll
        for (int b = 0; b < NB; ++b) {
            const float pg = acc[b][0] * inv_cnt;
            const float tg = acc[b][1] * inv_cnt;
            rl2 += sqrtf(acc[b][2]) / fmaxf(sqrtf(acc[b][3]), 1e-8f);
            ge  += fabsf(pg - tg) / fmaxf(tg, 1e-8f);
        }
        out[0] = rl2 * 0.25f + 0.1f * (ge * 0.25f);
    }
}

// =================== fallback path (if ws too small) ===================

__global__ __launch_bounds__(256) void sobolev_main_fb(
    const float4* __restrict__ pred,
    const float4* __restrict__ target,
    const int*    __restrict__ knn,
    const float*  __restrict__ pos,
    float*        __restrict__ part)
{
    const int xcd   = blockIdx.x & 7;
    const int s     = blockIdx.x >> 3;
    const int b     = xcd >> 1;
    const int thalf = xcd & 1;
    const int w     = s * 256 + threadIdx.x;
    const int k     = w & (NK - 1);
    const int n     = w >> 4;
    const int j     = knn[(b << 18) + w];

    const float* pc = pos + (b * NPTS + n) * 3;
    const float* pj = pos + (b * NPTS + j) * 3;
    const float dx = pj[0] - pc[0], dy = pj[1] - pc[1], dz = pj[2] - pc[2];
    const float d2   = fmaxf(dx*dx + dy*dy + dz*dz, 1e-8f);
    const float dist = fmaxf(sqrtf(d2), 1e-8f);
    const float inv_d = 1.0f / dist;

    float pg_abs = 0.f, tg_abs = 0.f, sd = 0.f, st = 0.f;
    const bool do_l2 = (k == 0);
    const int t0 = thalf * 4;
    #pragma unroll
    for (int tt = 0; tt < 4; ++tt) {
        const int base = (b * NT + t0 + tt) * NPTS;
        const float4 pcv = pred[base + n];
        const float4 pjv = pred[base + j];
        const float4 tcv = target[base + n];
        const float4 tjv = target[base + j];
        pg_abs += fabsf(pjv.x-pcv.x)+fabsf(pjv.y-pcv.y)+fabsf(pjv.z-pcv.z)+fabsf(pjv.w-pcv.w);
        tg_abs += fabsf(tjv.x-tcv.x)+fabsf(tjv.y-tcv.y)+fabsf(tjv.z-tcv.z)+fabsf(tjv.w-tcv.w);
        if (do_l2) {
            const float ex = pcv.x-tcv.x, ey = pcv.y-tcv.y, ez = pcv.z-tcv.z, ew = pcv.w-tcv.w;
            sd += ex*ex + ey*ey + ez*ez + ew*ew;
            st += tcv.x*tcv.x + tcv.y*tcv.y + tcv.z*tcv.z + tcv.w*tcv.w;
        }
    }
    float vals[4] = { pg_abs * inv_d, tg_abs * inv_d, sd, st };
    __shared__ float lds[4][4];
    const int wave = threadIdx.x >> 6, lane = threadIdx.x & 63;
    #pragma unroll
    for (int c = 0; c < 4; ++c) {
        float v = vals[c];
        #pragma unroll
        for (int o = 32; o > 0; o >>= 1) v += __shfl_down(v, o);
        if (lane == 0) lds[wave][c] = v;
    }
    __syncthreads();
    if (threadIdx.x < 4) {
        const int slot = (xcd << 10) | s;
        part[slot * 4 + threadIdx.x] =
            lds[0][threadIdx.x] + lds[1][threadIdx.x] +
            lds[2][threadIdx.x] + lds[3][threadIdx.x];
    }
}

__global__ __launch_bounds__(256) void sobolev_finalize_fb(
    const float* __restrict__ part, float* __restrict__ out)
{
    __shared__ float sums_s[16];
    __shared__ float lred[4];
    const int tid = threadIdx.x;
    for (int bc = 0; bc < 16; ++bc) {
        const int b = bc >> 2, comp = bc & 3;
        float s = 0.f;
        for (int i = tid; i < 2048; i += 256)
            s += part[(b * 2048 + i) * 4 + comp];
        #pragma unroll
        for (int o = 32; o > 0; o >>= 1) s += __shfl_down(s, o);
        const int wave = tid >> 6, lane = tid & 63;
        if (lane == 0) lred[wave] = s;
        __syncthreads();
        if (tid == 0) sums_s[bc] = lred[0] + lred[1] + lred[2] + lred[3];
        __syncthreads();
    }
    if (tid == 0) {
        float rl2 = 0.f, ge = 0.f;
        const float inv_cnt = 1.0f / GRAD_COUNT;
        #pragma unroll
        for (int b = 0; b < NB; ++b) {
            const float pg = sums_s[b*4+0] * inv_cnt;
            const float tg = sums_s[b*4+1] * inv_cnt;
            rl2 += sqrtf(sums_s[b*4+2]) / fmaxf(sqrtf(sums_s[b*4+3]), 1e-8f);
            ge  += fabsf(pg - tg) / fmaxf(tg, 1e-8f);
        }
        out[0] = rl2 * 0.25f + 0.1f * (ge * 0.25f);
    }
}

// =================== launch ===================

extern "C" void kernel_launch(void* const* d_in, const int* in_sizes, int n_in,
                              void* d_out, int out_size, void* d_ws, size_t ws_size,
                              hipStream_t stream) {
    const float4* pred   = (const float4*)d_in[0];
    const float4* target = (const float4*)d_in[1];
    const int*    knn    = (const int*)d_in[2];
    const float*  pos    = (const float*)d_in[3];
    float* out = (float*)d_out;

    if (ws_size >= (size_t)WS_NEEDED) {
        uint4*    P     = (uint4*)d_ws;
        unsigned* REC4  = (unsigned*)((char*)d_ws + REC_OFF_B);
        float*    partA = (float*)((char*)d_ws + PARTA_OFF_B);
        float*    partB = (float*)((char*)d_ws + PARTB_OFF_B);

        sobolev_prep<<<PREP_BLOCKS, 256, 0, stream>>>(pred, target, pos, knn,
                                                      P, REC4, partB);
        sobolev_grad<<<GRAD_BLOCKS, 256, 0, stream>>>(P, REC4, partA);
        sobolev_final<<<1, 1024, 0, stream>>>(partA, partB, out);
    } else {
        float* part = (float*)d_ws;      // 8192*4 floats = 128 KB
        sobolev_main_fb<<<8192, 256, 0, stream>>>(pred, target, knn, pos, part);
        sobolev_finalize_fb<<<1, 256, 0, stream>>>(part, out);
    }
}

// Round 12
// 30.576 us; speedup vs baseline: 6.0094x; 1.1397x over previous
//
#include <hip/hip_runtime.h>
#include <hip/hip_fp8.h>

#define NB   4
#define NT   8
#define NPTS 16384
#define NK   16
#define GRAD_COUNT 8388608.0f   // T*N*K*C per batch

// ---- workspace layout (bytes) ----
// P     : [B][N] 64-B fp8 field blocks (4 x uint4)       = 4 MB
// REC4  : [B][N][K] u32 {bf16(inv_d)<<16 | j}            = 4 MB
// partA : [B][1024][2] f32 (grad partials)               = 32 KB
// partB : [B][256][2]  f32 (rl2 partials)                = 8 KB
#define P_BYTES     (NB * NPTS * 64)
#define REC_OFF_B   P_BYTES
#define PARTA_OFF_B (REC_OFF_B + NB * NPTS * NK * 4)
#define PARTB_OFF_B (PARTA_OFF_B + 32768)
#define WS_NEEDED   (PARTB_OFF_B + 8192)

#define PACK_BLOCKS 1024
#define DIST_BLOCKS 1024          // 4 tuples/thread
#define PREP_BLOCKS (PACK_BLOCKS + DIST_BLOCKS)
#define GRAD_BLOCKS 4096

#if defined(__has_builtin)
#if __has_builtin(__builtin_amdgcn_cvt_pk_f32_fp8) && __has_builtin(__builtin_amdgcn_cvt_pk_fp8_f32)
#define USE_FP8_BUILTINS 1
#endif
#endif

typedef float vf2 __attribute__((ext_vector_type(2)));

__device__ __forceinline__ unsigned pack4_fp8(float a, float b, float c, float d) {
#ifdef USE_FP8_BUILTINS
    int u = __builtin_amdgcn_cvt_pk_fp8_f32(a, b, 0, false);
    u     = __builtin_amdgcn_cvt_pk_fp8_f32(c, d, u, true);
    return (unsigned)u;
#else
    __hip_fp8_e4m3 ha(a), hb(b), hc(c), hd(d);
    return (unsigned)ha.__x | ((unsigned)hb.__x << 8) |
           ((unsigned)hc.__x << 16) | ((unsigned)hd.__x << 24);
#endif
}

__device__ __forceinline__ float absdiff4(unsigned a, unsigned b) {
#ifdef USE_FP8_BUILTINS
    vf2 a0 = __builtin_amdgcn_cvt_pk_f32_fp8((int)a, false);
    vf2 a1 = __builtin_amdgcn_cvt_pk_f32_fp8((int)a, true);
    vf2 b0 = __builtin_amdgcn_cvt_pk_f32_fp8((int)b, false);
    vf2 b1 = __builtin_amdgcn_cvt_pk_f32_fp8((int)b, true);
    return fabsf(a0.x - b0.x) + fabsf(a0.y - b0.y) +
           fabsf(a1.x - b1.x) + fabsf(a1.y - b1.y);
#else
    float s = 0.f;
    #pragma unroll
    for (int i = 0; i < 4; ++i) {
        __hip_fp8_e4m3 ha, hb;
        ha.__x = (a >> (8 * i)) & 0xff;
        hb.__x = (b >> (8 * i)) & 0xff;
        s += fabsf((float)ha - (float)hb);
    }
    return s;
#endif
}

// =================== prep: pack blocks || dist blocks ===================

__global__ __launch_bounds__(256) void sobolev_prep(
    const float4* __restrict__ pred,
    const float4* __restrict__ target,
    const float*  __restrict__ pos,
    const int*    __restrict__ knn,
    uint4*    __restrict__ P,        // [b][n] 4 x uint4
    unsigned* __restrict__ REC4,     // [b][n][k]
    float*    __restrict__ partB)    // [b][256][2]
{
    if (blockIdx.x < PACK_BLOCKS) {
        // ---- pack fields to fp8 + rl2 partials ----
        const int blk = blockIdx.x;            // b-major
        const int b   = blk >> 8;
        const int n   = ((blk & 255) << 6) + (threadIdx.x >> 2);
        const int q   = threadIdx.x & 3;       // lane q owns t = q, q+4

        const float4 pv0 = pred  [(b * NT + q    ) * NPTS + n];
        const float4 pv1 = pred  [(b * NT + q + 4) * NPTS + n];
        const float4 tv0 = target[(b * NT + q    ) * NPTS + n];
        const float4 tv1 = target[(b * NT + q + 4) * NPTS + n];

        uint4 ck;
        ck.x = pack4_fp8(pv0.x, pv0.y, pv0.z, pv0.w);
        ck.y = pack4_fp8(pv1.x, pv1.y, pv1.z, pv1.w);
        ck.z = pack4_fp8(tv0.x, tv0.y, tv0.z, tv0.w);
        ck.w = pack4_fp8(tv1.x, tv1.y, tv1.z, tv1.w);
        P[((size_t)(b * NPTS + n) << 2) + q] = ck;

        float sd, st;
        {
            const float e0 = pv0.x - tv0.x, e1 = pv0.y - tv0.y,
                        e2 = pv0.z - tv0.z, e3 = pv0.w - tv0.w;
            const float f0 = pv1.x - tv1.x, f1 = pv1.y - tv1.y,
                        f2 = pv1.z - tv1.z, f3 = pv1.w - tv1.w;
            sd = e0*e0 + e1*e1 + e2*e2 + e3*e3 + f0*f0 + f1*f1 + f2*f2 + f3*f3;
            st = tv0.x*tv0.x + tv0.y*tv0.y + tv0.z*tv0.z + tv0.w*tv0.w +
                 tv1.x*tv1.x + tv1.y*tv1.y + tv1.z*tv1.z + tv1.w*tv1.w;
        }

        __shared__ float lds[4][2];
        const int wave = threadIdx.x >> 6, lane = threadIdx.x & 63;
        #pragma unroll
        for (int o = 32; o > 0; o >>= 1) {
            sd += __shfl_down(sd, o);
            st += __shfl_down(st, o);
        }
        if (lane == 0) { lds[wave][0] = sd; lds[wave][1] = st; }
        __syncthreads();
        if (threadIdx.x < 2)
            partB[blk * 2 + threadIdx.x] =
                lds[0][threadIdx.x] + lds[1][threadIdx.x] +
                lds[2][threadIdx.x] + lds[3][threadIdx.x];
    } else {
        // ---- dist: 4 tuples/thread -> {bf16 inv_d, j} records ----
        const int t0 = ((blockIdx.x - PACK_BLOCKS) * 256 + threadIdx.x) * 4;
        const int b  = t0 >> 18;
        const int n  = (t0 >> 4) & (NPTS - 1);   // same n for all 4 (t0 % 16 in {0,4,8,12})

        const int4 js = *(const int4*)(knn + t0);

        const float* pb_ = pos + (size_t)b * NPTS * 3;
        const float nx = pb_[n * 3], ny = pb_[n * 3 + 1], nz = pb_[n * 3 + 2];

        uint4 recs;
        unsigned* rp = &recs.x;
        #pragma unroll
        for (int i = 0; i < 4; ++i) {
            const int j = (&js.x)[i];
            const float dx = pb_[j * 3    ] - nx;
            const float dy = pb_[j * 3 + 1] - ny;
            const float dz = pb_[j * 3 + 2] - nz;
            const float d2 = fmaxf(dx*dx + dy*dy + dz*dz, 1e-8f);
            // d2 >= 1e-8 => sqrt >= 1e-4 > eps, so 1/max(sqrt,eps) == rsqrt
            unsigned u = __float_as_uint(rsqrtf(d2));
            u += 0x8000u;                       // bf16 RN (ties away; fine here)
            rp[i] = (u & 0xffff0000u) | (unsigned)j;
        }
        *(uint4*)(REC4 + t0) = recs;
    }
}

// =================== grad: 4 n's / wave, 1 random 64-B line per tuple ===================

__global__ __launch_bounds__(256) void sobolev_grad(
    const uint4*    __restrict__ P,
    const unsigned* __restrict__ REC4,
    float*          __restrict__ partA)   // [b][1024][2]
{
    // XCD pinning: per-XCD reused set = P(b) 1MB (+ REC4 streamed)
    const int xcd  = blockIdx.x & 7;
    const int b    = xcd >> 1;
    const int nblk = ((xcd & 1) << 9) | (blockIdx.x >> 3);   // 0..1023
    const int wave = threadIdx.x >> 6;
    const int lane = threadIdx.x & 63;
    const int k    = lane >> 2;       // 16 neighbor slots per wave
    const int q    = lane & 3;        // 4 lanes cover one 64-B block
    const int nb   = (nblk << 4) | (wave << 2);   // 4 n's per wave

    const size_t pb = (size_t)(b * NPTS);
    float v0 = 0.f, v1 = 0.f;

    #pragma unroll
    for (int i = 0; i < 4; ++i) {
        const int n = nb + i;
        const unsigned r = REC4[(((b << 14) | n) << 4) | k];
        const int j = (int)(r & 0xffffu);
        const float inv_d = __uint_as_float(r & 0xffff0000u);

        const uint4 gj = P[((pb + j) << 2) + q];
        const uint4 gn = P[((pb + n) << 2) + q];

        const float sp = absdiff4(gj.x, gn.x) + absdiff4(gj.y, gn.y);
        const float st = absdiff4(gj.z, gn.z) + absdiff4(gj.w, gn.w);
        v0 += sp * inv_d;
        v1 += st * inv_d;
    }

    __shared__ float lds[4][2];
    #pragma unroll
    for (int o = 32; o > 0; o >>= 1) {
        v0 += __shfl_down(v0, o);
        v1 += __shfl_down(v1, o);
    }
    if (lane == 0) { lds[wave][0] = v0; lds[wave][1] = v1; }
    __syncthreads();
    if (threadIdx.x < 2) {
        const int slot = (b << 10) | nblk;
        partA[slot * 2 + threadIdx.x] =
            lds[0][threadIdx.x] + lds[1][threadIdx.x] +
            lds[2][threadIdx.x] + lds[3][threadIdx.x];
    }
}

// =================== final: all 4 batches in parallel ===================

__global__ __launch_bounds__(1024) void sobolev_final(
    const float* __restrict__ partA,   // [4][1024][2]
    const float* __restrict__ partB,   // [4][256][2]
    float*       __restrict__ out)
{
    const int tid  = threadIdx.x;
    const int b    = tid >> 8;          // wave-aligned: waves 4b..4b+3 hold batch b
    const int slot = tid & 255;
    __shared__ float red[16][4];        // [wave][{pg,tg,sd,st}]

    float pg = 0.f, tg = 0.f;
    const float2* pa2 = (const float2*)(partA + b * 1024 * 2);
    #pragma unroll
    for (int i = 0; i < 4; ++i) {
        const float2 v = pa2[slot + i * 256];
        pg += v.x; tg += v.y;
    }
    const float2 vb = ((const float2*)(partB + b * 256 * 2))[slot];
    float sd = vb.x, st = vb.y;

    #pragma unroll
    for (int o = 32; o > 0; o >>= 1) {
        pg += __shfl_down(pg, o); tg += __shfl_down(tg, o);
        sd += __shfl_down(sd, o); st += __shfl_down(st, o);
    }
    const int wave = tid >> 6, lane = tid & 63;
    if (lane == 0) {
        red[wave][0] = pg; red[wave][1] = tg;
        red[wave][2] = sd; red[wave][3] = st;
    }
    __syncthreads();

    if (tid == 0) {
        float rl2 = 0.f, ge = 0.f;
        const float inv_cnt = 1.0f / GRAD_COUNT;
        #pragma unroll
        for (int bb = 0; bb < NB; ++bb) {
            float apg = 0.f, atg = 0.f, asd = 0.f, ast = 0.f;
            #pragma unroll
            for (int w = 0; w < 4; ++w) {
                apg += red[bb * 4 + w][0];
                atg += red[bb * 4 + w][1];
                asd += red[bb * 4 + w][2];
                ast += red[bb * 4 + w][3];
            }
            const float pgm = apg * inv_cnt;
            const float tgm = atg * inv_cnt;
            rl2 += sqrtf(asd) / fmaxf(sqrtf(ast), 1e-8f);
            ge  += fabsf(pgm - tgm) / fmaxf(tgm, 1e-8f);
        }
        out[0] = rl2 * 0.25f + 0.1f * (ge * 0.25f);
    }
}

// =================== fallback path (if ws too small) ===================

__global__ __launch_bounds__(256) void sobolev_main_fb(
    const float4* __restrict__ pred,
    const float4* __restrict__ target,
    const int*    __restrict__ knn,
    const float*  __restrict__ pos,
    float*        __restrict__ part)
{
    const int xcd   = blockIdx.x & 7;
    const int s     = blockIdx.x >> 3;
    const int b     = xcd >> 1;
    const int thalf = xcd & 1;
    const int w     = s * 256 + threadIdx.x;
    const int k     = w & (NK - 1);
    const int n     = w >> 4;
    const int j     = knn[(b << 18) + w];

    const float* pc = pos + (b * NPTS + n) * 3;
    const float* pj = pos + (b * NPTS + j) * 3;
    const float dx = pj[0] - pc[0], dy = pj[1] - pc[1], dz = pj[2] - pc[2];
    const float d2   = fmaxf(dx*dx + dy*dy + dz*dz, 1e-8f);
    const float dist = fmaxf(sqrtf(d2), 1e-8f);
    const float inv_d = 1.0f / dist;

    float pg_abs = 0.f, tg_abs = 0.f, sd = 0.f, st = 0.f;
    const bool do_l2 = (k == 0);
    const int t0 = thalf * 4;
    #pragma unroll
    for (int tt = 0; tt < 4; ++tt) {
        const int base = (b * NT + t0 + tt) * NPTS;
        const float4 pcv = pred[base + n];
        const float4 pjv = pred[base + j];
        const float4 tcv = target[base + n];
        const float4 tjv = target[base + j];
        pg_abs += fabsf(pjv.x-pcv.x)+fabsf(pjv.y-pcv.y)+fabsf(pjv.z-pcv.z)+fabsf(pjv.w-pcv.w);
        tg_abs += fabsf(tjv.x-tcv.x)+fabsf(tjv.y-tcv.y)+fabsf(tjv.z-tcv.z)+fabsf(tjv.w-tcv.w);
        if (do_l2) {
            const float ex = pcv.x-tcv.x, ey = pcv.y-tcv.y, ez = pcv.z-tcv.z, ew = pcv.w-tcv.w;
            sd += ex*ex + ey*ey + ez*ez + ew*ew;
            st += tcv.x*tcv.x + tcv.y*tcv.y + tcv.z*tcv.z + tcv.w*tcv.w;
        }
    }
    float vals[4] = { pg_abs * inv_d, tg_abs * inv_d, sd, st };
    __shared__ float lds[4][4];
    const int wave = threadIdx.x >> 6, lane = threadIdx.x & 63;
    #pragma unroll
    for (int c = 0; c < 4; ++c) {
        float v = vals[c];
        #pragma unroll
        for (int o = 32; o > 0; o >>= 1) v += __shfl_down(v, o);
        if (lane == 0) lds[wave][c] = v;
    }
    __syncthreads();
    if (threadIdx.x < 4) {
        const int slot = (xcd << 10) | s;
        part[slot * 4 + threadIdx.x] =
            lds[0][threadIdx.x] + lds[1][threadIdx.x] +
            lds[2][threadIdx.x] + lds[3][threadIdx.x];
    }
}

__global__ __launch_bounds__(256) void sobolev_finalize_fb(
    const float* __restrict__ part, float* __restrict__ out)
{
    __shared__ float sums_s[16];
    __shared__ float lred[4];
    const int tid = threadIdx.x;
    for (int bc = 0; bc < 16; ++bc) {
        const int b = bc >> 2, comp = bc & 3;
        float s = 0.f;
        for (int i = tid; i < 2048; i += 256)
            s += part[(b * 2048 + i) * 4 + comp];
        #pragma unroll
        for (int o = 32; o > 0; o >>= 1) s += __shfl_down(s, o);
        const int wave = tid >> 6, lane = tid & 63;
        if (lane == 0) lred[wave] = s;
        __syncthreads();
        if (tid == 0) sums_s[bc] = lred[0] + lred[1] + lred[2] + lred[3];
        __syncthreads();
    }
    if (tid == 0) {
        float rl2 = 0.f, ge = 0.f;
        const float inv_cnt = 1.0f / GRAD_COUNT;
        #pragma unroll
        for (int b = 0; b < NB; ++b) {
            const float pg = sums_s[b*4+0] * inv_cnt;
            const float tg = sums_s[b*4+1] * inv_cnt;
            rl2 += sqrtf(sums_s[b*4+2]) / fmaxf(sqrtf(sums_s[b*4+3]), 1e-8f);
            ge  += fabsf(pg - tg) / fmaxf(tg, 1e-8f);
        }
        out[0] = rl2 * 0.25f + 0.1f * (ge * 0.25f);
    }
}

// =================== launch ===================

extern "C" void kernel_launch(void* const* d_in, const int* in_sizes, int n_in,
                              void* d_out, int out_size, void* d_ws, size_t ws_size,
                              hipStream_t stream) {
    const float4* pred   = (const float4*)d_in[0];
    const float4* target = (const float4*)d_in[1];
    const int*    knn    = (const int*)d_in[2];
    const float*  pos    = (const float*)d_in[3];
    float* out = (float*)d_out;

    if (ws_size >= (size_t)WS_NEEDED) {
        uint4*    P     = (uint4*)d_ws;
        unsigned* REC4  = (unsigned*)((char*)d_ws + REC_OFF_B);
        float*    partA = (float*)((char*)d_ws + PARTA_OFF_B);
        float*    partB = (float*)((char*)d_ws + PARTB_OFF_B);

        sobolev_prep<<<PREP_BLOCKS, 256, 0, stream>>>(pred, target, pos, knn,
                                                      P, REC4, partB);
        sobolev_grad<<<GRAD_BLOCKS, 256, 0, stream>>>(P, REC4, partA);
        sobolev_final<<<1, 1024, 0, stream>>>(partA, partB, out);
    } else {
        float* part = (float*)d_ws;      // 8192*4 floats = 128 KB
        sobolev_main_fb<<<8192, 256, 0, stream>>>(pred, target, knn, pos, part);
        sobolev_finalize_fb<<<1, 256, 0, stream>>>(part, out);
    }
}

// Round 13
// 29.680 us; speedup vs baseline: 6.1909x; 1.0302x over previous
//
#include <hip/hip_runtime.h>
#include <hip/hip_fp8.h>

#define NB   4
#define NT   8
#define NPTS 16384
#define NK   16
#define GRAD_COUNT 8388608.0f   // T*N*K*C per batch

// ---- workspace layout (bytes) ----
// P     : [B][N] 64-B fp8 field blocks (4 x uint4)       = 4 MB
// REC4  : [B][N][K] u32 {bf16(inv_d)<<16 | j}            = 4 MB
// partA : [B][512][2] f32 (grad partials)                = 16 KB
// partB : [B][256][2] f32 (rl2 partials)                 = 8 KB
#define P_BYTES     (NB * NPTS * 64)
#define REC_OFF_B   P_BYTES
#define PARTA_OFF_B (REC_OFF_B + NB * NPTS * NK * 4)
#define PARTB_OFF_B (PARTA_OFF_B + 16384)
#define WS_NEEDED   (PARTB_OFF_B + 8192)

#define PACK_BLOCKS 1024
#define DIST_BLOCKS 1024          // 4 tuples/thread
#define PREP_BLOCKS (PACK_BLOCKS + DIST_BLOCKS)
#define GRAD_BLOCKS 2048          // 8 n's per wave

#if defined(__has_builtin)
#if __has_builtin(__builtin_amdgcn_cvt_pk_f32_fp8) && __has_builtin(__builtin_amdgcn_cvt_pk_fp8_f32)
#define USE_FP8_BUILTINS 1
#endif
#endif

typedef float vf2 __attribute__((ext_vector_type(2)));

__device__ __forceinline__ unsigned pack4_fp8(float a, float b, float c, float d) {
#ifdef USE_FP8_BUILTINS
    int u = __builtin_amdgcn_cvt_pk_fp8_f32(a, b, 0, false);
    u     = __builtin_amdgcn_cvt_pk_fp8_f32(c, d, u, true);
    return (unsigned)u;
#else
    __hip_fp8_e4m3 ha(a), hb(b), hc(c), hd(d);
    return (unsigned)ha.__x | ((unsigned)hb.__x << 8) |
           ((unsigned)hc.__x << 16) | ((unsigned)hd.__x << 24);
#endif
}

__device__ __forceinline__ float absdiff4(unsigned a, unsigned b) {
#ifdef USE_FP8_BUILTINS
    vf2 a0 = __builtin_amdgcn_cvt_pk_f32_fp8((int)a, false);
    vf2 a1 = __builtin_amdgcn_cvt_pk_f32_fp8((int)a, true);
    vf2 b0 = __builtin_amdgcn_cvt_pk_f32_fp8((int)b, false);
    vf2 b1 = __builtin_amdgcn_cvt_pk_f32_fp8((int)b, true);
    return fabsf(a0.x - b0.x) + fabsf(a0.y - b0.y) +
           fabsf(a1.x - b1.x) + fabsf(a1.y - b1.y);
#else
    float s = 0.f;
    #pragma unroll
    for (int i = 0; i < 4; ++i) {
        __hip_fp8_e4m3 ha, hb;
        ha.__x = (a >> (8 * i)) & 0xff;
        hb.__x = (b >> (8 * i)) & 0xff;
        s += fabsf((float)ha - (float)hb);
    }
    return s;
#endif
}

// =================== prep: pack blocks || dist blocks ===================

__global__ __launch_bounds__(256) void sobolev_prep(
    const float4* __restrict__ pred,
    const float4* __restrict__ target,
    const float*  __restrict__ pos,
    const int*    __restrict__ knn,
    uint4*    __restrict__ P,        // [b][n] 4 x uint4
    unsigned* __restrict__ REC4,     // [b][n][k]
    float*    __restrict__ partB)    // [b][256][2]
{
    if (blockIdx.x < PACK_BLOCKS) {
        // ---- pack fields to fp8 + rl2 partials ----
        const int blk = blockIdx.x;            // b-major
        const int b   = blk >> 8;
        const int n   = ((blk & 255) << 6) + (threadIdx.x >> 2);
        const int q   = threadIdx.x & 3;       // lane q owns t = q, q+4

        const float4 pv0 = pred  [(b * NT + q    ) * NPTS + n];
        const float4 pv1 = pred  [(b * NT + q + 4) * NPTS + n];
        const float4 tv0 = target[(b * NT + q    ) * NPTS + n];
        const float4 tv1 = target[(b * NT + q + 4) * NPTS + n];

        uint4 ck;
        ck.x = pack4_fp8(pv0.x, pv0.y, pv0.z, pv0.w);
        ck.y = pack4_fp8(pv1.x, pv1.y, pv1.z, pv1.w);
        ck.z = pack4_fp8(tv0.x, tv0.y, tv0.z, tv0.w);
        ck.w = pack4_fp8(tv1.x, tv1.y, tv1.z, tv1.w);
        P[((size_t)(b * NPTS + n) << 2) + q] = ck;

        float sd, st;
        {
            const float e0 = pv0.x - tv0.x, e1 = pv0.y - tv0.y,
                        e2 = pv0.z - tv0.z, e3 = pv0.w - tv0.w;
            const float f0 = pv1.x - tv1.x, f1 = pv1.y - tv1.y,
                        f2 = pv1.z - tv1.z, f3 = pv1.w - tv1.w;
            sd = e0*e0 + e1*e1 + e2*e2 + e3*e3 + f0*f0 + f1*f1 + f2*f2 + f3*f3;
            st = tv0.x*tv0.x + tv0.y*tv0.y + tv0.z*tv0.z + tv0.w*tv0.w +
                 tv1.x*tv1.x + tv1.y*tv1.y + tv1.z*tv1.z + tv1.w*tv1.w;
        }

        __shared__ float lds[4][2];
        const int wave = threadIdx.x >> 6, lane = threadIdx.x & 63;
        #pragma unroll
        for (int o = 32; o > 0; o >>= 1) {
            sd += __shfl_down(sd, o);
            st += __shfl_down(st, o);
        }
        if (lane == 0) { lds[wave][0] = sd; lds[wave][1] = st; }
        __syncthreads();
        if (threadIdx.x < 2)
            partB[blk * 2 + threadIdx.x] =
                lds[0][threadIdx.x] + lds[1][threadIdx.x] +
                lds[2][threadIdx.x] + lds[3][threadIdx.x];
    } else {
        // ---- dist: 4 tuples/thread -> {bf16 inv_d, j} records ----
        const int t0 = ((blockIdx.x - PACK_BLOCKS) * 256 + threadIdx.x) * 4;
        const int b  = t0 >> 18;
        const int n  = (t0 >> 4) & (NPTS - 1);   // same n for all 4 (t0 % 16 in {0,4,8,12})

        const int4 js = *(const int4*)(knn + t0);

        const float* pb_ = pos + (size_t)b * NPTS * 3;
        const float nx = pb_[n * 3], ny = pb_[n * 3 + 1], nz = pb_[n * 3 + 2];

        uint4 recs;
        unsigned* rp = &recs.x;
        #pragma unroll
        for (int i = 0; i < 4; ++i) {
            const int j = (&js.x)[i];
            const float dx = pb_[j * 3    ] - nx;
            const float dy = pb_[j * 3 + 1] - ny;
            const float dz = pb_[j * 3 + 2] - nz;
            const float d2 = fmaxf(dx*dx + dy*dy + dz*dz, 1e-8f);
            // d2 >= 1e-8 => sqrt >= 1e-4 > eps, so 1/max(sqrt,eps) == rsqrt
            unsigned u = __float_as_uint(rsqrtf(d2));
            u += 0x8000u;                       // bf16 RN (ties away; fine here)
            rp[i] = (u & 0xffff0000u) | (unsigned)j;
        }
        *(uint4*)(REC4 + t0) = recs;
    }
}

// =================== grad: 8 n's / wave, 1 random 64-B line per tuple ===================

__global__ __launch_bounds__(256) void sobolev_grad(
    const uint4*    __restrict__ P,
    const unsigned* __restrict__ REC4,
    float*          __restrict__ partA)   // [b][512][2]
{
    // XCD pinning: per-XCD reused set = P(b) 1MB (+ REC4 streamed)
    const int xcd  = blockIdx.x & 7;
    const int b    = xcd >> 1;
    const int nblk = ((xcd & 1) << 8) | (blockIdx.x >> 3);   // 0..511
    const int wave = threadIdx.x >> 6;
    const int lane = threadIdx.x & 63;
    const int k    = lane >> 2;       // 16 neighbor slots per wave
    const int q    = lane & 3;        // 4 lanes cover one 64-B block
    const int nb   = (nblk << 5) | (wave << 3);   // 8 n's per wave

    const size_t pb = (size_t)(b * NPTS);

    // issue all REC reads first (independent), then gathers
    unsigned r[8];
    #pragma unroll
    for (int i = 0; i < 8; ++i)
        r[i] = REC4[(((b << 14) | (nb + i)) << 4) | k];

    float v0 = 0.f, v1 = 0.f;
    #pragma unroll
    for (int i = 0; i < 8; ++i) {
        const int n = nb + i;
        const int j = (int)(r[i] & 0xffffu);
        const float inv_d = __uint_as_float(r[i] & 0xffff0000u);

        const uint4 gj = P[((pb + j) << 2) + q];
        const uint4 gn = P[((pb + n) << 2) + q];

        const float sp = absdiff4(gj.x, gn.x) + absdiff4(gj.y, gn.y);
        const float st = absdiff4(gj.z, gn.z) + absdiff4(gj.w, gn.w);
        v0 += sp * inv_d;
        v1 += st * inv_d;
    }

    __shared__ float lds[4][2];
    #pragma unroll
    for (int o = 32; o > 0; o >>= 1) {
        v0 += __shfl_down(v0, o);
        v1 += __shfl_down(v1, o);
    }
    if (lane == 0) { lds[wave][0] = v0; lds[wave][1] = v1; }
    __syncthreads();
    if (threadIdx.x < 2) {
        const int slot = (b << 9) | nblk;
        partA[slot * 2 + threadIdx.x] =
            lds[0][threadIdx.x] + lds[1][threadIdx.x] +
            lds[2][threadIdx.x] + lds[3][threadIdx.x];
    }
}

// =================== final: all 4 batches in parallel ===================

__global__ __launch_bounds__(1024) void sobolev_final(
    const float* __restrict__ partA,   // [4][512][2]
    const float* __restrict__ partB,   // [4][256][2]
    float*       __restrict__ out)
{
    const int tid  = threadIdx.x;
    const int b    = tid >> 8;          // wave-aligned: waves 4b..4b+3 hold batch b
    const int slot = tid & 255;
    __shared__ float red[16][4];        // [wave][{pg,tg,sd,st}]

    float pg = 0.f, tg = 0.f;
    const float2* pa2 = (const float2*)(partA + b * 512 * 2);
    {
        const float2 v0 = pa2[slot];
        const float2 v1 = pa2[slot + 256];
        pg = v0.x + v1.x; tg = v0.y + v1.y;
    }
    const float2 vb = ((const float2*)(partB + b * 256 * 2))[slot];
    float sd = vb.x, st = vb.y;

    #pragma unroll
    for (int o = 32; o > 0; o >>= 1) {
        pg += __shfl_down(pg, o); tg += __shfl_down(tg, o);
        sd += __shfl_down(sd, o); st += __shfl_down(st, o);
    }
    const int wave = tid >> 6, lane = tid & 63;
    if (lane == 0) {
        red[wave][0] = pg; red[wave][1] = tg;
        red[wave][2] = sd; red[wave][3] = st;
    }
    __syncthreads();

    if (tid == 0) {
        float rl2 = 0.f, ge = 0.f;
        const float inv_cnt = 1.0f / GRAD_COUNT;
        #pragma unroll
        for (int bb = 0; bb < NB; ++bb) {
            float apg = 0.f, atg = 0.f, asd = 0.f, ast = 0.f;
            #pragma unroll
            for (int w = 0; w < 4; ++w) {
                apg += red[bb * 4 + w][0];
                atg += red[bb * 4 + w][1];
                asd += red[bb * 4 + w][2];
                ast += red[bb * 4 + w][3];
            }
            const float pgm = apg * inv_cnt;
            const float tgm = atg * inv_cnt;
            rl2 += sqrtf(asd) / fmaxf(sqrtf(ast), 1e-8f);
            ge  += fabsf(pgm - tgm) / fmaxf(tgm, 1e-8f);
        }
        out[0] = rl2 * 0.25f + 0.1f * (ge * 0.25f);
    }
}

// =================== fallback path (if ws too small) ===================

__global__ __launch_bounds__(256) void sobolev_main_fb(
    const float4* __restrict__ pred,
    const float4* __restrict__ target,
    const int*    __restrict__ knn,
    const float*  __restrict__ pos,
    float*        __restrict__ part)
{
    const int xcd   = blockIdx.x & 7;
    const int s     = blockIdx.x >> 3;
    const int b     = xcd >> 1;
    const int thalf = xcd & 1;
    const int w     = s * 256 + threadIdx.x;
    const int k     = w & (NK - 1);
    const int n     = w >> 4;
    const int j     = knn[(b << 18) + w];

    const float* pc = pos + (b * NPTS + n) * 3;
    const float* pj = pos + (b * NPTS + j) * 3;
    const float dx = pj[0] - pc[0], dy = pj[1] - pc[1], dz = pj[2] - pc[2];
    const float d2   = fmaxf(dx*dx + dy*dy + dz*dz, 1e-8f);
    const float dist = fmaxf(sqrtf(d2), 1e-8f);
    const float inv_d = 1.0f / dist;

    float pg_abs = 0.f, tg_abs = 0.f, sd = 0.f, st = 0.f;
    const bool do_l2 = (k == 0);
    const int t0 = thalf * 4;
    #pragma unroll
    for (int tt = 0; tt < 4; ++tt) {
        const int base = (b * NT + t0 + tt) * NPTS;
        const float4 pcv = pred[base + n];
        const float4 pjv = pred[base + j];
        const float4 tcv = target[base + n];
        const float4 tjv = target[base + j];
        pg_abs += fabsf(pjv.x-pcv.x)+fabsf(pjv.y-pcv.y)+fabsf(pjv.z-pcv.z)+fabsf(pjv.w-pcv.w);
        tg_abs += fabsf(tjv.x-tcv.x)+fabsf(tjv.y-tcv.y)+fabsf(tjv.z-tcv.z)+fabsf(tjv.w-tcv.w);
        if (do_l2) {
            const float ex = pcv.x-tcv.x, ey = pcv.y-tcv.y, ez = pcv.z-tcv.z, ew = pcv.w-tcv.w;
            sd += ex*ex + ey*ey + ez*ez + ew*ew;
            st += tcv.x*tcv.x + tcv.y*tcv.y + tcv.z*tcv.z + tcv.w*tcv.w;
        }
    }
    float vals[4] = { pg_abs * inv_d, tg_abs * inv_d, sd, st };
    __shared__ float lds[4][4];
    const int wave = threadIdx.x >> 6, lane = threadIdx.x & 63;
    #pragma unroll
    for (int c = 0; c < 4; ++c) {
        float v = vals[c];
        #pragma unroll
        for (int o = 32; o > 0; o >>= 1) v += __shfl_down(v, o);
        if (lane == 0) lds[wave][c] = v;
    }
    __syncthreads();
    if (threadIdx.x < 4) {
        const int slot = (xcd << 10) | s;
        part[slot * 4 + threadIdx.x] =
            lds[0][threadIdx.x] + lds[1][threadIdx.x] +
            lds[2][threadIdx.x] + lds[3][threadIdx.x];
    }
}

__global__ __launch_bounds__(256) void sobolev_finalize_fb(
    const float* __restrict__ part, float* __restrict__ out)
{
    __shared__ float sums_s[16];
    __shared__ float lred[4];
    const int tid = threadIdx.x;
    for (int bc = 0; bc < 16; ++bc) {
        const int b = bc >> 2, comp = bc & 3;
        float s = 0.f;
        for (int i = tid; i < 2048; i += 256)
            s += part[(b * 2048 + i) * 4 + comp];
        #pragma unroll
        for (int o = 32; o > 0; o >>= 1) s += __shfl_down(s, o);
        const int wave = tid >> 6, lane = tid & 63;
        if (lane == 0) lred[wave] = s;
        __syncthreads();
        if (tid == 0) sums_s[bc] = lred[0] + lred[1] + lred[2] + lred[3];
        __syncthreads();
    }
    if (tid == 0) {
        float rl2 = 0.f, ge = 0.f;
        const float inv_cnt = 1.0f / GRAD_COUNT;
        #pragma unroll
        for (int b = 0; b < NB; ++b) {
            const float pg = sums_s[b*4+0] * inv_cnt;
            const float tg = sums_s[b*4+1] * inv_cnt;
            rl2 += sqrtf(sums_s[b*4+2]) / fmaxf(sqrtf(sums_s[b*4+3]), 1e-8f);
            ge  += fabsf(pg - tg) / fmaxf(tg, 1e-8f);
        }
        out[0] = rl2 * 0.25f + 0.1f * (ge * 0.25f);
    }
}

// =================== launch ===================

extern "C" void kernel_launch(void* const* d_in, const int* in_sizes, int n_in,
                              void* d_out, int out_size, void* d_ws, size_t ws_size,
                              hipStream_t stream) {
    const float4* pred   = (const float4*)d_in[0];
    const float4* target = (const float4*)d_in[1];
    const int*    knn    = (const int*)d_in[2];
    const float*  pos    = (const float*)d_in[3];
    float* out = (float*)d_out;

    if (ws_size >= (size_t)WS_NEEDED) {
        uint4*    P     = (uint4*)d_ws;
        unsigned* REC4  = (unsigned*)((char*)d_ws + REC_OFF_B);
        float*    partA = (float*)((char*)d_ws + PARTA_OFF_B);
        float*    partB = (float*)((char*)d_ws + PARTB_OFF_B);

        sobolev_prep<<<PREP_BLOCKS, 256, 0, stream>>>(pred, target, pos, knn,
                                                      P, REC4, partB);
        sobolev_grad<<<GRAD_BLOCKS, 256, 0, stream>>>(P, REC4, partA);
        sobolev_final<<<1, 1024, 0, stream>>>(partA, partB, out);
    } else {
        float* part = (float*)d_ws;      // 8192*4 floats = 128 KB
        sobolev_main_fb<<<8192, 256, 0, stream>>>(pred, target, knn, pos, part);
        sobolev_finalize_fb<<<1, 256, 0, stream>>>(part, out);
    }
}